// Round 1
// baseline (77.992 us; speedup 1.0000x reference)
//
#include <hip/hip_runtime.h>

#define BB 384   // batch
#define DD 128   // embedding dim
#define NI 3     // number of losses
#define SS 25    // seq len in target

// ---------------------------------------------------------------------------
// Kernel A: normalize embeddings, compute per-row sq = sum(e*e), compute labels
// grid = NI*BB blocks x 64 threads (1 wave). Row r = blockIdx.x.
// Blocks with r < BB additionally compute the label arrays (thread 0).
// ---------------------------------------------------------------------------
__global__ __launch_bounds__(64) void prep_kernel(
    const float* __restrict__ vr,       // [NI, BB, DD]
    const float* __restrict__ target,   // [BB, SS, NI]
    const int*   __restrict__ label_item, // [BB]
    float* __restrict__ e,              // [NI, BB, DD]
    float* __restrict__ sq,             // [NI, BB]
    float* __restrict__ lab)            // [NI, BB]
{
    const int row = blockIdx.x;         // 0 .. NI*BB-1
    const int t   = threadIdx.x;        // 0 .. 63
    const float* x = vr + (size_t)row * DD;
    float x0 = x[t], x1 = x[t + 64];
    float ss = x0 * x0 + x1 * x1;
    #pragma unroll
    for (int off = 32; off > 0; off >>= 1) ss += __shfl_down(ss, off, 64);
    ss = __shfl(ss, 0, 64);
    float norm = sqrtf(ss);
    norm = fmaxf(norm, 1e-12f);
    const float inv = 1.0f / norm;
    const float e0 = x0 * inv, e1 = x1 * inv;
    e[(size_t)row * DD + t]      = e0;
    e[(size_t)row * DD + t + 64] = e1;
    float s2 = e0 * e0 + e1 * e1;
    #pragma unroll
    for (int off = 32; off > 0; off >>= 1) s2 += __shfl_down(s2, off, 64);
    if (t == 0) sq[row] = s2;

    // labels (one block per b for r < BB)
    if (row < BB && t == 0) {
        const float lf = (float)label_item[row];
        lab[row]          = lf;   // i = 0
        lab[BB + row]     = lf;   // i = 1
        float m = 0.0f;
        for (int s = 0; s < SS; ++s)
            m += target[(size_t)row * SS * NI + (size_t)s * NI + 2];
        lab[2 * BB + row] = m / (float)SS;   // i = 2
    }
}

// ---------------------------------------------------------------------------
// Kernel B: per (i, anchor a) block. Build dist row in LDS, then each thread
// owns candidate positive p = tid and sweeps all negatives n. Block-reduce.
// grid = NI*BB blocks x 384 threads.
// ---------------------------------------------------------------------------
__global__ __launch_bounds__(384) void triplet_kernel(
    const float* __restrict__ e,        // [NI, BB, DD]
    const float* __restrict__ sq,       // [NI, BB]
    const float* __restrict__ lab,      // [NI, BB]
    float* __restrict__ tot_part,       // [NI, BB]
    int*   __restrict__ cnt_part)       // [NI, BB]
{
    const int blk = blockIdx.x;         // 0 .. NI*BB-1
    const int i   = blk / BB;
    const int a   = blk % BB;
    const int t   = threadIdx.x;        // 0 .. 383

    __shared__ float ea[DD];
    __shared__ float drow[BB];
    __shared__ float labs[BB];
    __shared__ float red_f[512];
    __shared__ int   red_i[512];

    const float* ei = e + (size_t)i * BB * DD;
    if (t < DD) ea[t] = ei[(size_t)a * DD + t];
    labs[t] = lab[i * BB + t];
    __syncthreads();

    // distance row: dist[a][t]
    const float* eb = ei + (size_t)t * DD;
    float dot = 0.0f;
    #pragma unroll 8
    for (int k = 0; k < DD; ++k) dot = fmaf(ea[k], eb[k], dot);
    const float d2 = sq[i * BB + a] + sq[i * BB + t] - 2.0f * dot;
    drow[t] = sqrtf(fmaxf(d2, 0.0f));
    __syncthreads();

    const float la = labs[a];
    float tot = 0.0f;
    int   cnt = 0;
    if (labs[t] == la && t != a) {      // t is a valid positive p
        const float dp = drow[t];
        for (int n = 0; n < BB; ++n) {
            if (labs[n] != la) {
                const float tm = drow[n] - dp;   // an - ap
                // keep iff 0 < tm < 1  (tm>0 & tm<=MARGIN & (1-tm)>0, MARGIN=1)
                if (tm > 0.0f && tm < 1.0f) {
                    cnt += 1;
                    tot += 1.0f - tm;
                }
            }
        }
    }
    red_f[t] = tot;
    red_i[t] = cnt;
    if (t < 128) { red_f[384 + t] = 0.0f; red_i[384 + t] = 0; }
    __syncthreads();
    #pragma unroll
    for (int off = 256; off > 0; off >>= 1) {
        if (t < off) { red_f[t] += red_f[t + off]; red_i[t] += red_i[t + off]; }
        __syncthreads();
    }
    if (t == 0) {
        tot_part[i * BB + a] = red_f[0];
        cnt_part[i * BB + a] = red_i[0];
    }
}

// ---------------------------------------------------------------------------
// Kernel C: reduce partials per i, compute losses, write [loss_sum, l0,l1,l2]
// 1 block x 384 threads.
// ---------------------------------------------------------------------------
__global__ __launch_bounds__(384) void finalize_kernel(
    const float* __restrict__ tot_part,
    const int*   __restrict__ cnt_part,
    float* __restrict__ out)
{
    __shared__ float rf[512];
    __shared__ int   ri[512];
    __shared__ float lsum;
    const int t = threadIdx.x;
    if (t == 0) lsum = 0.0f;
    for (int i = 0; i < NI; ++i) {
        rf[t] = tot_part[i * BB + t];
        ri[t] = cnt_part[i * BB + t];
        if (t < 128) { rf[384 + t] = 0.0f; ri[384 + t] = 0; }
        __syncthreads();
        #pragma unroll
        for (int off = 256; off > 0; off >>= 1) {
            if (t < off) { rf[t] += rf[t + off]; ri[t] += ri[t + off]; }
            __syncthreads();
        }
        if (t == 0) {
            const float li = (ri[0] > 0) ? (rf[0] / (float)ri[0]) : 0.0f;
            out[1 + i] = li;
            lsum += li;
        }
        __syncthreads();
    }
    if (t == 0) out[0] = lsum;
}

extern "C" void kernel_launch(void* const* d_in, const int* in_sizes, int n_in,
                              void* d_out, int out_size, void* d_ws, size_t ws_size,
                              hipStream_t stream) {
    // inputs: 0=input(unused), 1=vr_classes, 2=target, 3=target_class(unused),
    //         4=label_item, 5=optimizers_idx(unused)
    const float* vr         = (const float*)d_in[1];
    const float* target     = (const float*)d_in[2];
    const int*   label_item = (const int*)d_in[4];
    float* out = (float*)d_out;

    float* ws  = (float*)d_ws;
    float* e        = ws;                       // NI*BB*DD
    float* sq       = e + (size_t)NI * BB * DD; // NI*BB
    float* lab      = sq + NI * BB;             // NI*BB
    float* tot_part = lab + NI * BB;            // NI*BB
    int*   cnt_part = (int*)(tot_part + NI * BB); // NI*BB

    prep_kernel<<<NI * BB, 64, 0, stream>>>(vr, target, label_item, e, sq, lab);
    triplet_kernel<<<NI * BB, 384, 0, stream>>>(e, sq, lab, tot_part, cnt_part);
    finalize_kernel<<<1, 384, 0, stream>>>(tot_part, cnt_part, out);
}

// Round 2
// 42.769 us; speedup vs baseline: 1.8236x; 1.8236x over previous
//
#include <hip/hip_runtime.h>

#define BB 384   // batch
#define DD 128   // embedding dim
#define NI 3     // number of losses
#define SS 25    // seq len in target

// ---------------------------------------------------------------------------
// Kernel A: normalize embeddings, compute per-row sq = sum(e*e), compute labels
// grid = NI*BB blocks x 64 threads (1 wave). Row r = blockIdx.x.
// ---------------------------------------------------------------------------
__global__ __launch_bounds__(64) void prep_kernel(
    const float* __restrict__ vr,         // [NI, BB, DD]
    const float* __restrict__ target,     // [BB, SS, NI]
    const int*   __restrict__ label_item, // [BB]
    float* __restrict__ e,                // [NI, BB, DD]
    float* __restrict__ sq,               // [NI, BB]
    float* __restrict__ lab)              // [NI, BB]
{
    const int row = blockIdx.x;           // 0 .. NI*BB-1
    const int t   = threadIdx.x;          // 0 .. 63
    const float* x = vr + (size_t)row * DD;
    float x0 = x[t], x1 = x[t + 64];
    float ss = x0 * x0 + x1 * x1;
    #pragma unroll
    for (int off = 32; off > 0; off >>= 1) ss += __shfl_down(ss, off, 64);
    ss = __shfl(ss, 0, 64);
    float norm = fmaxf(sqrtf(ss), 1e-12f);
    const float inv = 1.0f / norm;
    const float e0 = x0 * inv, e1 = x1 * inv;
    e[(size_t)row * DD + t]      = e0;
    e[(size_t)row * DD + t + 64] = e1;
    float s2 = e0 * e0 + e1 * e1;
    #pragma unroll
    for (int off = 32; off > 0; off >>= 1) s2 += __shfl_down(s2, off, 64);
    if (t == 0) sq[row] = s2;

    if (row < BB && t == 0) {
        const float lf = (float)label_item[row];
        lab[row]          = lf;   // i = 0
        lab[BB + row]     = lf;   // i = 1
        float m = 0.0f;
        for (int s = 0; s < SS; ++s)
            m += target[(size_t)row * SS * NI + (size_t)s * NI + 2];
        lab[2 * BB + row] = m / (float)SS;   // i = 2
    }
}

// ---------------------------------------------------------------------------
// Kernel B: per (i, anchor a) block. Compute own distance d_t = dist(a,t),
// stream-compact positives/negatives into LDS lists, then each thread owns
// one compacted NEGATIVE and sweeps the (few) positives.
// grid = NI*BB blocks x 384 threads.
// ---------------------------------------------------------------------------
__global__ __launch_bounds__(384) void triplet_kernel(
    const float* __restrict__ e,        // [NI, BB, DD]
    const float* __restrict__ sq,       // [NI, BB]
    const float* __restrict__ lab,      // [NI, BB]
    float* __restrict__ tot_part,       // [NI, BB]
    int*   __restrict__ cnt_part)       // [NI, BB]
{
    const int blk  = blockIdx.x;        // 0 .. NI*BB-1
    const int i    = blk / BB;
    const int a    = blk % BB;
    const int t    = threadIdx.x;       // 0 .. 383
    const int lane = t & 63;
    const int wid  = t >> 6;            // 0 .. 5

    __shared__ float ea[DD];
    __shared__ float labs[BB];
    __shared__ float dp_list[BB];
    __shared__ float dn_list[BB];
    __shared__ int   wp[6], wn[6];
    __shared__ float rf[6];
    __shared__ int   ri[6];

    const float* ei = e + (size_t)i * BB * DD;
    if (t < DD / 4)
        ((float4*)ea)[t] = ((const float4*)(ei + (size_t)a * DD))[t];
    labs[t] = lab[i * BB + t];
    __syncthreads();

    // d_t = dist(a, t), vectorized
    const float4* eb = (const float4*)(ei + (size_t)t * DD);
    float dot = 0.0f;
    #pragma unroll 8
    for (int k = 0; k < DD / 4; ++k) {
        const float4 b  = eb[k];
        const float4 av = ((const float4*)ea)[k];
        dot = fmaf(av.x, b.x, dot);
        dot = fmaf(av.y, b.y, dot);
        dot = fmaf(av.z, b.z, dot);
        dot = fmaf(av.w, b.w, dot);
    }
    const float d2 = sq[i * BB + a] + sq[i * BB + t] - 2.0f * dot;
    const float d  = sqrtf(fmaxf(d2, 0.0f));

    // stream compaction of positives / negatives
    const float la   = labs[a];
    const bool isPos = (labs[t] == la) && (t != a);
    const bool isNeg = (labs[t] != la);
    const unsigned long long mp = __ballot(isPos);
    const unsigned long long mn = __ballot(isNeg);
    const unsigned long long lowmask =
        (lane == 0) ? 0ull : (~0ull >> (64 - lane));
    const int rp = __popcll(mp & lowmask);
    const int rn = __popcll(mn & lowmask);
    if (lane == 0) { wp[wid] = __popcll(mp); wn[wid] = __popcll(mn); }
    __syncthreads();
    int posOff = 0, negOff = 0, P = 0, Nn = 0;
    #pragma unroll
    for (int w = 0; w < 6; ++w) {
        if (w < wid) { posOff += wp[w]; negOff += wn[w]; }
        P  += wp[w];
        Nn += wn[w];
    }
    if (isPos) dp_list[posOff + rp] = d;
    if (isNeg) dn_list[negOff + rn] = d;
    __syncthreads();

    // pair sweep: thread owns negative t, loops over compacted positives
    float tot = 0.0f;
    int   cnt = 0;
    if (t < Nn) {
        const float dn = dn_list[t];
        for (int p = 0; p < P; ++p) {
            const float tm = dn - dp_list[p];   // an - ap
            if (tm > 0.0f && tm < 1.0f) { cnt += 1; tot += 1.0f - tm; }
        }
    }

    // wave reduce, then 6-partial sum
    #pragma unroll
    for (int off = 32; off > 0; off >>= 1) {
        tot += __shfl_down(tot, off, 64);
        cnt += __shfl_down(cnt, off, 64);
    }
    if (lane == 0) { rf[wid] = tot; ri[wid] = cnt; }
    __syncthreads();
    if (t == 0) {
        float T = 0.0f; int C = 0;
        #pragma unroll
        for (int w = 0; w < 6; ++w) { T += rf[w]; C += ri[w]; }
        tot_part[i * BB + a] = T;
        cnt_part[i * BB + a] = C;
    }
}

// ---------------------------------------------------------------------------
// Kernel C: reduce partials per i, compute losses, write [loss_sum, l0,l1,l2]
// 1 block x 384 threads.
// ---------------------------------------------------------------------------
__global__ __launch_bounds__(384) void finalize_kernel(
    const float* __restrict__ tot_part,
    const int*   __restrict__ cnt_part,
    float* __restrict__ out)
{
    __shared__ float rf[512];
    __shared__ int   ri[512];
    __shared__ float lsum;
    const int t = threadIdx.x;
    if (t == 0) lsum = 0.0f;
    for (int i = 0; i < NI; ++i) {
        rf[t] = tot_part[i * BB + t];
        ri[t] = cnt_part[i * BB + t];
        if (t < 128) { rf[384 + t] = 0.0f; ri[384 + t] = 0; }
        __syncthreads();
        #pragma unroll
        for (int off = 256; off > 0; off >>= 1) {
            if (t < off) { rf[t] += rf[t + off]; ri[t] += ri[t + off]; }
            __syncthreads();
        }
        if (t == 0) {
            const float li = (ri[0] > 0) ? (rf[0] / (float)ri[0]) : 0.0f;
            out[1 + i] = li;
            lsum += li;
        }
        __syncthreads();
    }
    if (t == 0) out[0] = lsum;
}

extern "C" void kernel_launch(void* const* d_in, const int* in_sizes, int n_in,
                              void* d_out, int out_size, void* d_ws, size_t ws_size,
                              hipStream_t stream) {
    const float* vr         = (const float*)d_in[1];
    const float* target     = (const float*)d_in[2];
    const int*   label_item = (const int*)d_in[4];
    float* out = (float*)d_out;

    float* ws  = (float*)d_ws;
    float* e        = ws;                         // NI*BB*DD
    float* sq       = e + (size_t)NI * BB * DD;   // NI*BB
    float* lab      = sq + NI * BB;               // NI*BB
    float* tot_part = lab + NI * BB;              // NI*BB
    int*   cnt_part = (int*)(tot_part + NI * BB); // NI*BB

    prep_kernel<<<NI * BB, 64, 0, stream>>>(vr, target, label_item, e, sq, lab);
    triplet_kernel<<<NI * BB, 384, 0, stream>>>(e, sq, lab, tot_part, cnt_part);
    finalize_kernel<<<1, 384, 0, stream>>>(tot_part, cnt_part, out);
}